// Round 6
// baseline (106.679 us; speedup 1.0000x reference)
//
#include <hip/hip_runtime.h>
#include <stdint.h>

// covpool: y[b] = (1/M) Xc Xc^T = (X/16)(X/16)^T - mu mu^T   (M=256)
// 64x64 output tiles, upper-triangular only: 36 tiles/batch x 64 batches = 2304
// blocks = exactly 9/CU (balanced). Fused staging (fp32->bf16/16 + row sums),
// bf16 MFMA SYRK, rank-1 mean correction in epilogue, LDS-transpose mirror store.

typedef __attribute__((ext_vector_type(8))) short bf16x8;   // 8 bf16 = 4 VGPRs
typedef __attribute__((ext_vector_type(4))) float f32x4;

static __device__ __forceinline__ unsigned short f2bf(float f) {
    union { float f; uint32_t u; } c; c.f = f;
    uint32_t u = c.u;
    return (unsigned short)((u + 0x7FFFu + ((u >> 16) & 1u)) >> 16);  // RNE
}

static __device__ __forceinline__ void cvt_store(f32x4 v0, f32x4 v1, float* psum,
                                                 unsigned short* dst) {
    v0 *= 0.0625f; v1 *= 0.0625f;
    *psum += (v0.x + v0.y + v0.z + v0.w) + (v1.x + v1.y + v1.z + v1.w);
    bf16x8 o;
    o[0] = (short)f2bf(v0.x); o[1] = (short)f2bf(v0.y);
    o[2] = (short)f2bf(v0.z); o[3] = (short)f2bf(v0.w);
    o[4] = (short)f2bf(v1.x); o[5] = (short)f2bf(v1.y);
    o[6] = (short)f2bf(v1.z); o[7] = (short)f2bf(v1.w);
    *(bf16x8*)dst = o;
}

__global__ __launch_bounds__(256, 4) void covpool_fused(const float* __restrict__ x,
                                                        float* __restrict__ y) {
    // union: staging tiles (8 KB) / epilogue buffer Ep[64][67] f32 (17152 B)
    __shared__ __align__(16) char smem[64 * 67 * 4];
    unsigned short* As = (unsigned short*)smem;            // 64x32 bf16, swizzled slots
    unsigned short* Bs = (unsigned short*)(smem + 4096);
    float* Ep = (float*)smem;                              // stride 67
    __shared__ float muA[64];
    __shared__ float muB[64];

    // 2304 blocks: blockIdx%8 -> XCD; each XCD gets 8 batches x 36 tiles
    const int xcd = blockIdx.x & 7;
    const int j   = blockIdx.x >> 3;         // 0..287
    const int b   = xcd * 8 + j / 36;        // 0..63
    int t = j % 36;                          // upper-tri tile index
    int tm = 0;
    while (t >= 8 - tm) { t -= (8 - tm); ++tm; }
    const int tn = tm + t;
    const bool diag = (tm == tn);

    const float* Ag = x + ((size_t)b * 512 + tm * 64) * 256;
    const float* Bg = x + ((size_t)b * 512 + tn * 64) * 256;

    const int tid  = threadIdx.x;
    const int lane = tid & 63;
    const int wave = tid >> 6;
    const int wm = (wave >> 1) * 32;         // wave's 32x32 subtile
    const int wn = (wave & 1) * 32;

    f32x4 acc[2][2] = {};
    float pA = 0.f, pB = 0.f;

    const int rl  = lane & 15;
    const int q   = lane >> 4;
    const int swl = (q ^ ((rl >> 1) & 3)) * 8;   // swizzled read slot (shorts)
    const int srow = tid >> 2, schunk = tid & 3; // staging: row 0..63, chunk 0..3
    const int sslot = schunk ^ ((srow >> 1) & 3);

    // prefetch kk=0
    f32x4 a0, a1, b0, b1;
    {
        const float* g = Ag + (size_t)srow * 256 + schunk * 8;
        a0 = *(const f32x4*)g; a1 = *(const f32x4*)(g + 4);
        if (!diag) {
            const float* h = Bg + (size_t)srow * 256 + schunk * 8;
            b0 = *(const f32x4*)h; b1 = *(const f32x4*)(h + 4);
        }
    }

    for (int kk = 0; kk < 256; kk += 32) {
        __syncthreads();                     // prev iter's fragment reads done
        cvt_store(a0, a1, &pA, As + srow * 32 + sslot * 8);
        if (!diag) cvt_store(b0, b1, &pB, Bs + srow * 32 + sslot * 8);
        __syncthreads();
        if (kk < 224) {                      // issue next chunk early
            const float* g = Ag + (size_t)srow * 256 + (kk + 32) + schunk * 8;
            a0 = *(const f32x4*)g; a1 = *(const f32x4*)(g + 4);
            if (!diag) {
                const float* h = Bg + (size_t)srow * 256 + (kk + 32) + schunk * 8;
                b0 = *(const f32x4*)h; b1 = *(const f32x4*)(h + 4);
            }
        }
        const unsigned short* Bsrc = diag ? As : Bs;
        bf16x8 af[2], bfr[2];
#pragma unroll
        for (int i = 0; i < 2; ++i)
            af[i] = *(const bf16x8*)(As + (wm + i * 16 + rl) * 32 + swl);
#pragma unroll
        for (int jj = 0; jj < 2; ++jj)
            bfr[jj] = *(const bf16x8*)(Bsrc + (wn + jj * 16 + rl) * 32 + swl);
#pragma unroll
        for (int i = 0; i < 2; ++i)
#pragma unroll
            for (int jj = 0; jj < 2; ++jj)
                acc[i][jj] = __builtin_amdgcn_mfma_f32_16x16x32_bf16(
                    af[i], bfr[jj], acc[i][jj], 0, 0, 0);
    }

    // row means: 4 staging threads per row; staged vals are x/16 so mu = rowsum/16
    {
        float s = pA;
        s += __shfl_xor(s, 1, 64); s += __shfl_xor(s, 2, 64);
        if (schunk == 0) muA[srow] = s * 0.0625f;
        if (!diag) {
            float sb = pB;
            sb += __shfl_xor(sb, 1, 64); sb += __shfl_xor(sb, 2, 64);
            if (schunk == 0) muB[srow] = sb * 0.0625f;
        }
    }
    __syncthreads();                         // mu ready; all LDS frag reads drained

    // Each wave writes its corrected 32x32 into Ep (disjoint regions)
    const float* muBp = diag ? muA : muB;
#pragma unroll
    for (int i = 0; i < 2; ++i)
#pragma unroll
        for (int jj = 0; jj < 2; ++jj) {
            const int col = wn + jj * 16 + rl;
            const float mb = muBp[col];
#pragma unroll
            for (int r = 0; r < 4; ++r) {
                const int row = wm + i * 16 + q * 4 + r;
                Ep[row * 67 + col] = acc[i][jj][r] - muA[row] * mb;
            }
        }
    __syncthreads();

    float* yb = y + (size_t)b * 512 * 512;
    // normal orientation: contiguous 256B row runs, f32x4
#pragma unroll
    for (int v = 0; v < 4; ++v) {
        const int flat = v * 256 + tid;      // 0..1023
        const int row = flat >> 4, c4 = flat & 15;
        f32x4 val = *(const f32x4*)(Ep + row * 67 + c4 * 4);
        *(f32x4*)(yb + (size_t)(tm * 64 + row) * 512 + tn * 64 + c4 * 4) = val;
    }
    if (!diag) {  // mirror tile: read Ep transposed (stride-67 cols: 2-way, free)
#pragma unroll
        for (int v = 0; v < 4; ++v) {
            const int id = v * 256 + tid;    // 0..1023
            const int cc = id >> 4, g = id & 15;
            f32x4 val;
#pragma unroll
            for (int e = 0; e < 4; ++e)
                val[e] = Ep[(g * 4 + e) * 67 + cc];
            *(f32x4*)(yb + (size_t)(tn * 64 + cc) * 512 + tm * 64 + g * 4) = val;
        }
    }
}

extern "C" void kernel_launch(void* const* d_in, const int* in_sizes, int n_in,
                              void* d_out, int out_size, void* d_ws, size_t ws_size,
                              hipStream_t stream) {
    const float* x = (const float*)d_in[0];
    float* yout = (float*)d_out;
    (void)d_ws; (void)ws_size;
    covpool_fused<<<2304, 256, 0, stream>>>(x, yout);
}